// Round 1
// baseline (213.978 us; speedup 1.0000x reference)
//
#include <hip/hip_runtime.h>

// Problem constants (fixed by setup_inputs)
constexpr int kB = 256;      // batch
constexpr int kN = 128;      // seq len
constexpr int kM = 512;      // mem width
constexpr int kSlots = 15;   // his_mem slots
constexpr int kS = 16;       // slots incl. null
constexpr int kW = 1536;     // attn_W row length (d_q + M)
constexpr int kCap = 8192;   // cached ambiguous-step capacity (n~66 measured)
constexpr int kMaxA = 128;   // max ambiguous steps per batch (= kN)
constexpr int kGrid = 512;   // persistent grid: 2 blocks/CU, co-resident
constexpr int kCsStride = 528;
constexpr int kBarStride = 16;  // uints per barrier counter (64B padding)

__device__ __forceinline__ float tanh_fast(float x)
{
    float xc = fminf(15.f, fmaxf(-15.f, x));
    float ex = __expf(2.f * xc);
    return 1.f - 2.f * __builtin_amdgcn_rcpf(ex + 1.f);
}

// Device-scope grid barrier: 64 padded counters, 8 arrivals each.
// All 512 blocks are co-resident (launch_bounds(256,2), LDS ~44KB -> 3/CU cap).
__device__ __forceinline__ void grid_barrier(unsigned* bar, unsigned phase)
{
    __syncthreads();
    if (threadIdx.x < 64) {
        if (threadIdx.x == 0) {
            __threadfence();   // release: writes visible device-wide
            atomicAdd(&bar[(blockIdx.x & 63) * kBarStride], 1u);
        }
        const unsigned tgt = phase * (kGrid / 64);
        while (__hip_atomic_load(&bar[threadIdx.x * kBarStride],
                                 __ATOMIC_RELAXED, __HIP_MEMORY_SCOPE_AGENT) < tgt)
            __builtin_amdgcn_s_sleep(2);
        __threadfence();       // acquire: invalidate stale cache before reads
    }
    __syncthreads();
}

// ---------------------------------------------------------------------------
// Single persistent kernel, 3 phases separated by device-scope grid barriers.
//   Phase 1 (blocks 0..255, block=batch): empty flags, hm copy, default log
//     rows, gumbel ambiguity filter + ballot-scan ordered per-batch step list
//     (LDS-persistent + mirrored to global for phase-2 consumers). No atomics.
//     Blocks 256..511 warm W into L2.
//   Phase 2 (all 512 blocks): 256-wide prefix scan of cnt[] (gives global step
//     numbering, amb-batch compaction, per-batch cache offset), then the c0
//     GEMM tiles and the q/cw GEMV chunks, grid-strided.
//   Phase 3 (blocks 0..255 with work): serial per-batch walk using persistent
//     LDS list/flags; e-eval from qCache + LDS C; writes copy cwCache rows.
// ---------------------------------------------------------------------------
__global__ __launch_bounds__(256, 2) void fused_k(
    const float* __restrict__ his_mem, const float* __restrict__ states,
    const float* __restrict__ states_mask, const float* __restrict__ global_trace,
    const float* __restrict__ null_mem, const float* __restrict__ gumbel_u,
    const float* __restrict__ W, const float* __restrict__ attn_b,
    const float* __restrict__ v, float* __restrict__ out, float* __restrict__ C0,
    float* __restrict__ qCache, float* __restrict__ cwCache,
    int* __restrict__ cnt_g, int* __restrict__ ambT_g, int* __restrict__ stepNz,
    unsigned* __restrict__ bar)
{
    const int tid = threadIdx.x;
    const int bid = blockIdx.x;

    // Scratch union: phase2 {As[1088]|Bs[1088]|Xs[1024]|scan ints @3200..3712}
    //                phase3 {Cs[8448]|vs[512]|Xb[1024]|Qb[512]}
    __shared__ __align__(16) float SCR[10496];
    // Persistent per-block state
    __shared__ float empty_p[kS];            // empty flags (phase3 mutates)
    __shared__ unsigned char ambList_p[kMaxA];
    __shared__ int Pex_p[kB + 1];            // exclusive prefix of cnt[]
    __shared__ short ambBatch_p[kB];
    __shared__ int wcnt_p[2];
    __shared__ int cntLoc_p, nab_p, T_p, Pb_p;
    __shared__ float e_sh[kS];
    __shared__ int slot_src[kSlots];
    __shared__ int k_sh, wk_sh, nz_sh;

    float* out_hm = out;
    float* out_log = out + (size_t)kB * kSlots * kM;

    // ======================= phase 1 =======================
    if (bid < kB) {
        const int b = bid;
        const int wave = tid >> 6, lane = tid & 63;
        for (int s = wave; s < kS; s += 4) {
            const float* p = (s < kSlots) ? his_mem + (size_t)(b * kSlots + s) * kM
                                          : null_mem + (size_t)b * kM;
            float4 v0 = *(const float4*)(p + lane * 4);
            float4 v1 = *(const float4*)(p + 256 + lane * 4);
            int nz = (v0.x != 0.f) | (v0.y != 0.f) | (v0.z != 0.f) | (v0.w != 0.f) |
                     (v1.x != 0.f) | (v1.y != 0.f) | (v1.z != 0.f) | (v1.w != 0.f);
            unsigned long long bal = __ballot(nz);
            if (lane == 0) empty_p[s] = (bal == 0ull) ? 1.f : 0.f;
            if (s < kSlots) {
                float* dst = out_hm + (size_t)(b * kSlots + s) * kM;
                *(float4*)(dst + lane * 4) = v0;
                *(float4*)(dst + 256 + lane * 4) = v1;
            }
        }
        __syncthreads();

        bool amb = false;
        if (tid < kN) {
            const int idx = b * kN + tid;
            const float* up = gumbel_u + (size_t)idx * kS;
            float g[kS];
#pragma unroll
            for (int s = 0; s < kS; ++s) {
                float u = fminf(fmaxf(up[s], 1e-20f), 1.0f);
                g[s] = -logf(-logf(u) + 1e-20f);
            }
            float rhs = g[15] + 10.f * empty_p[15] - 1.01f;
#pragma unroll
            for (int s = 0; s < kSlots; ++s)
                amb = amb || (g[s] + 10.f * empty_p[s] >= rhs);
            // default one-hot(15) log row (phase 3 overwrites flagged steps)
            float* lp = out_log + (size_t)idx * kS;
            float4 zz = make_float4(0.f, 0.f, 0.f, 0.f);
            *(float4*)(lp + 0) = zz;
            *(float4*)(lp + 4) = zz;
            *(float4*)(lp + 8) = zz;
            *(float4*)(lp + 12) = make_float4(0.f, 0.f, 0.f, 1.f);
        }
        unsigned long long m = __ballot(amb);   // per-wave mask
        if (tid < kN && (tid & 63) == 0) wcnt_p[tid >> 6] = __popcll(m);
        __syncthreads();
        if (tid < kN && amb) {
            int base = (tid >= 64) ? wcnt_p[0] : 0;
            int pos = base + __popcll(m & ((1ull << (tid & 63)) - 1ull));
            ambList_p[pos] = (unsigned char)tid;
            ambT_g[b * kMaxA + pos] = tid;
        }
        if (tid == 0) {
            int c = wcnt_p[0] + wcnt_p[1];
            cntLoc_p = c;
            cnt_g[b] = c;
        }
    } else {
        // warm W into L2 (phase 2 streams it heavily)
        const float* wp = W + (size_t)(bid - kB) * 3072;
        float acc = 0.f;
        for (int i = tid; i < 3072; i += 256) acc += wp[i];
        asm volatile("" :: "v"(acc));
    }

    grid_barrier(bar, 1);

    // ======================= phase 2 =======================
    {   // prefix scan of cnt[] (all blocks, redundant, ~1us)
        int* sc  = (int*)(SCR + 3200);
        int* sc2 = (int*)(SCR + 3456);
        int cv = cnt_g[tid];
        int iv = (cv > 0) ? 1 : 0;
        sc[tid] = cv;
        sc2[tid] = iv;
        for (int off = 1; off < kB; off <<= 1) {
            __syncthreads();
            int a  = (tid >= off) ? sc[tid - off] : 0;
            int a2 = (tid >= off) ? sc2[tid - off] : 0;
            __syncthreads();
            sc[tid] += a;
            sc2[tid] += a2;
        }
        __syncthreads();
        Pex_p[tid + 1] = sc[tid];
        if (iv) ambBatch_p[sc2[tid] - 1] = (short)tid;
        if (tid == 0) {
            Pex_p[0] = 0;
            T_p = sc[kB - 1];
            nab_p = sc2[kB - 1];
            Pb_p = (bid > 0 && bid < kB) ? sc[bid - 1] : 0;
        }
        __syncthreads();
    }

    const int nab = nab_p;
    int Tc = T_p;
    if (Tc > kCap) Tc = kCap;

    // ---- c0 GEMM tiles (<=512 tiles, one per block) ----
    if (nab > 0) {
        float* As = SCR;            // [16][68]
        float* Bs = SCR + 1088;     // [16][68]
        const int nTiles = ((nab + 3) >> 2) * 8;
        for (int tile = bid; tile < nTiles; tile += kGrid) {
            const int cx = tile >> 3;
            const int cy = tile & 7;
            const int n0 = cy * 64;
            const int row_l = tid >> 2;
            const int k4 = (tid & 3) * 4;
            const int ty = tid >> 4, tx = tid & 15;
            int bi = cx * 4 + (row_l >> 4);
            if (bi >= nab) bi = nab - 1;          // clamp: redundant work only
            const int b = ambBatch_p[bi];
            const int s = row_l & 15;
            const float* ap = (s < kSlots)
                                  ? (his_mem + (size_t)(b * kSlots + s) * kM)
                                  : (null_mem + (size_t)b * kM);
            const float* wp = W + (size_t)(n0 + row_l) * kW + 1024;

            float acc[4][4];
#pragma unroll
            for (int i = 0; i < 4; ++i)
#pragma unroll
                for (int j = 0; j < 4; ++j) acc[i][j] = 0.f;

            for (int kt = 0; kt < kM; kt += 16) {
                float4 a4 = *(const float4*)(ap + kt + k4);
                float4 b4 = *(const float4*)(wp + kt + k4);
                __syncthreads();
                As[(k4 + 0) * 68 + row_l] = a4.x; As[(k4 + 1) * 68 + row_l] = a4.y;
                As[(k4 + 2) * 68 + row_l] = a4.z; As[(k4 + 3) * 68 + row_l] = a4.w;
                Bs[(k4 + 0) * 68 + row_l] = b4.x; Bs[(k4 + 1) * 68 + row_l] = b4.y;
                Bs[(k4 + 2) * 68 + row_l] = b4.z; Bs[(k4 + 3) * 68 + row_l] = b4.w;
                __syncthreads();
#pragma unroll
                for (int k = 0; k < 16; ++k) {
                    const float4 av = *(const float4*)&As[k * 68 + ty * 4];
                    const float4 bv = *(const float4*)&Bs[k * 68 + tx * 4];
                    acc[0][0] = fmaf(av.x, bv.x, acc[0][0]);
                    acc[0][1] = fmaf(av.x, bv.y, acc[0][1]);
                    acc[0][2] = fmaf(av.x, bv.z, acc[0][2]);
                    acc[0][3] = fmaf(av.x, bv.w, acc[0][3]);
                    acc[1][0] = fmaf(av.y, bv.x, acc[1][0]);
                    acc[1][1] = fmaf(av.y, bv.y, acc[1][1]);
                    acc[1][2] = fmaf(av.y, bv.z, acc[1][2]);
                    acc[1][3] = fmaf(av.y, bv.w, acc[1][3]);
                    acc[2][0] = fmaf(av.z, bv.x, acc[2][0]);
                    acc[2][1] = fmaf(av.z, bv.y, acc[2][1]);
                    acc[2][2] = fmaf(av.z, bv.z, acc[2][2]);
                    acc[2][3] = fmaf(av.z, bv.w, acc[2][3]);
                    acc[3][0] = fmaf(av.w, bv.x, acc[3][0]);
                    acc[3][1] = fmaf(av.w, bv.y, acc[3][1]);
                    acc[3][2] = fmaf(av.w, bv.z, acc[3][2]);
                    acc[3][3] = fmaf(av.w, bv.w, acc[3][3]);
                }
            }
#pragma unroll
            for (int i = 0; i < 4; ++i) {
                int rl = ty * 4 + i;
                int bij = cx * 4 + (rl >> 4);
                if (bij >= nab) bij = nab - 1;
                int ro = (int)ambBatch_p[bij] * kS + (rl & 15);
                float4 o = make_float4(acc[i][0], acc[i][1], acc[i][2], acc[i][3]);
                *(float4*)(C0 + (size_t)ro * kM + n0 + tx * 4) = o;
            }
        }
    }

    // ---- q/cw GEMV chunks ----
    {
        float* Xs = SCR + 2176;     // [1024]
        for (int c = bid; c < Tc * 16; c += kGrid) {
            const int i = c >> 4;
            const int j = c & 15;
            // binary search: batch b with Pex[b] <= i < Pex[b+1] (uniform)
            int lo = 0, hi = kB - 1;
            while (lo < hi) {
                int mid = (lo + hi + 1) >> 1;
                if (Pex_p[mid] <= i) lo = mid; else hi = mid - 1;
            }
            const int b = lo;
            const int t = ambT_g[b * kMaxA + (i - Pex_p[b])];
            const int idx = b * kN + t;
            __syncthreads();             // protect Xs reuse across iterations
            if (tid == 0) nz_sh = 0;
            __syncthreads();
            float s0 = states[(size_t)idx * kM + tid];
            float s1 = states[(size_t)idx * kM + 256 + tid];
            Xs[tid] = s0; Xs[256 + tid] = s1;
            Xs[512 + tid] = global_trace[(size_t)b * kM + tid];
            Xs[768 + tid] = global_trace[(size_t)b * kM + 256 + tid];
            if (s0 != 0.f || s1 != 0.f) nz_sh = 1;
            __syncthreads();

            const int g = tid >> 4;
            const int l = tid & 15;
#pragma unroll
            for (int p = 0; p < 2; ++p) {
                const int r = j * 32 + p * 16 + g;
                const float* wr = W + (size_t)r * kW;
                float accq = 0.f, accc = 0.f;
#pragma unroll
                for (int jj = 0; jj < 16; ++jj) {
                    int k = l * 4 + jj * 64;
                    float4 w4 = *(const float4*)(wr + k);
                    float4 x4 = *(const float4*)&Xs[k];
                    accq = fmaf(w4.x, x4.x, accq); accq = fmaf(w4.y, x4.y, accq);
                    accq = fmaf(w4.z, x4.z, accq); accq = fmaf(w4.w, x4.w, accq);
                }
#pragma unroll
                for (int jj = 0; jj < 8; ++jj) {
                    int k = l * 4 + jj * 64;
                    float4 w4 = *(const float4*)(wr + 1024 + k);
                    float4 x4 = *(const float4*)&Xs[k];
                    accc = fmaf(w4.x, x4.x, accc); accc = fmaf(w4.y, x4.y, accc);
                    accc = fmaf(w4.z, x4.z, accc); accc = fmaf(w4.w, x4.w, accc);
                }
                accq += __shfl_xor(accq, 1); accq += __shfl_xor(accq, 2);
                accq += __shfl_xor(accq, 4); accq += __shfl_xor(accq, 8);
                accc += __shfl_xor(accc, 1); accc += __shfl_xor(accc, 2);
                accc += __shfl_xor(accc, 4); accc += __shfl_xor(accc, 8);
                if (l == 0) {
                    qCache[(size_t)i * kM + r] = accq + attn_b[r];
                    cwCache[(size_t)i * kM + r] = accc;
                }
            }
            if (tid == 0 && j == 0) stepNz[i] = nz_sh;
        }
    }

    grid_barrier(bar, 2);

    // ======================= phase 3 =======================
    if (bid >= kB) return;
    const int b = bid;
    const int cnt = cntLoc_p;
    if (cnt == 0) return;                 // defaults already correct

    float* Cs  = SCR;                     // [16][528]
    float* vsd = SCR + 8448;              // [512]
    float* Xb  = SCR + 8960;              // [1024] fallback staging
    float* Qb  = SCR + 9984;              // [512]  fallback q

    for (int i = tid; i < kS * kM; i += 256) {
        int s = i >> 9, mcol = i & 511;
        Cs[s * kCsStride + mcol] = C0[(size_t)(b * kS + s) * kM + mcol];
    }
    for (int i = tid; i < kM; i += 256) {
        vsd[i] = v[i];
        Xb[512 + i] = global_trace[(size_t)b * kM + i];
    }
    if (tid < kSlots) slot_src[tid] = -1;
    __syncthreads();

    const int sidx = tid >> 4;
    const int ml = tid & 15;
    const int Pb = Pb_p;

    for (int jj = 0; jj < cnt; ++jj) {
        const int t = ambList_p[jj];
        const int pos = Pb + jj;
        const float* qp;
        if (pos < kCap) {
            qp = qCache + (size_t)pos * kM;
        } else {
            // fallback: recompute q inline (dead for real inputs)
            Xb[tid] = states[(size_t)(b * kN + t) * kM + tid];
            Xb[256 + tid] = states[(size_t)(b * kN + t) * kM + 256 + tid];
            __syncthreads();
            const int g2 = tid >> 4, l2 = tid & 15;
            for (int r0 = 0; r0 < kM; r0 += 16) {
                int r = r0 + g2;
                const float* wr = W + (size_t)r * kW;
                float a = 0.f;
                for (int k = l2 * 4; k < 1024; k += 64) {
                    float4 w4 = *(const float4*)(wr + k);
                    float4 x4 = *(const float4*)&Xb[k];
                    a = fmaf(w4.x, x4.x, a); a = fmaf(w4.y, x4.y, a);
                    a = fmaf(w4.z, x4.z, a); a = fmaf(w4.w, x4.w, a);
                }
                a += __shfl_xor(a, 1); a += __shfl_xor(a, 2);
                a += __shfl_xor(a, 4); a += __shfl_xor(a, 8);
                if (l2 == 0) Qb[r] = a + attn_b[r];
            }
            __syncthreads();
            qp = Qb;
        }

        // e[s] = sum_m v[m] * tanh(q[m] + C[s][m])
        const float* crow = &Cs[sidx * kCsStride];
        float acc = 0.f;
#pragma unroll
        for (int j = 0; j < 8; ++j) {
            int mcol = ml * 4 + j * 64;
            float4 q4 = *(const float4*)(qp + mcol);
            float4 c4 = *(const float4*)&crow[mcol];
            float4 v4 = *(const float4*)&vsd[mcol];
            acc = fmaf(v4.x, tanh_fast(q4.x + c4.x), acc);
            acc = fmaf(v4.y, tanh_fast(q4.y + c4.y), acc);
            acc = fmaf(v4.z, tanh_fast(q4.z + c4.z), acc);
            acc = fmaf(v4.w, tanh_fast(q4.w + c4.w), acc);
        }
        acc += __shfl_xor(acc, 1); acc += __shfl_xor(acc, 2);
        acc += __shfl_xor(acc, 4); acc += __shfl_xor(acc, 8);
        if (ml == 0) e_sh[sidx] = acc;
        __syncthreads();

        // wave 0: softmax + empty mask + gumbel + argmax
        if (tid < 64) {
            int s = tid;
            float ev = (s < kS) ? e_sh[s] : -3.0e38f;
            float mx = ev;
            mx = fmaxf(mx, __shfl_xor(mx, 1));
            mx = fmaxf(mx, __shfl_xor(mx, 2));
            mx = fmaxf(mx, __shfl_xor(mx, 4));
            mx = fmaxf(mx, __shfl_xor(mx, 8));
            float w = (s < kS) ? __expf(ev - mx) : 0.f;
            float sm = w;
            sm += __shfl_xor(sm, 1); sm += __shfl_xor(sm, 2);
            sm += __shfl_xor(sm, 4); sm += __shfl_xor(sm, 8);
            w = w / sm;
            w += 10.0f * ((s < kS) ? empty_p[s] : 0.f);
            float z;
            if (s < kS) {
                float u = gumbel_u[(size_t)(b * kN + t) * kS + s];
                u = fminf(fmaxf(u, 1e-20f), 1.0f);
                float g = -logf(-logf(u) + 1e-20f);
                z = w + g;            // tau = 1.0
            } else z = -3.0e38f;
            float zm = z;
            zm = fmaxf(zm, __shfl_xor(zm, 1));
            zm = fmaxf(zm, __shfl_xor(zm, 2));
            zm = fmaxf(zm, __shfl_xor(zm, 4));
            zm = fmaxf(zm, __shfl_xor(zm, 8));
            unsigned long long bal = __ballot(z == zm) & 0xFFFFull;
            if (s == 0) k_sh = __ffsll(bal) - 1;   // first-max (jnp.argmax)
        }
        __syncthreads();

        const int k = k_sh;
        if (tid < kS)
            out_log[(size_t)(b * kN + t) * kS + tid] = (tid == k) ? 1.f : 0.f;
        if (tid == 0) {
            float mv = states_mask[b * kN + t];
            wk_sh = (k < kSlots && mv != 0.0f) ? k : -1;
            nz_sh = 0;
        }
        __syncthreads();

        const int wk = wk_sh;
        if (wk >= 0) {
            if (pos < kCap) {
                Cs[wk * kCsStride + tid] = cwCache[(size_t)pos * kM + tid];
                Cs[wk * kCsStride + 256 + tid] = cwCache[(size_t)pos * kM + 256 + tid];
                if (tid == 0) {
                    slot_src[wk] = t;
                    empty_p[wk] = stepNz[pos] ? 0.f : 1.f;
                }
            } else {
                // fallback: inline cw GEMV from staged Xb (dead normally)
                if (Xb[tid] != 0.f || Xb[256 + tid] != 0.f) nz_sh = 1;
                __syncthreads();
                const int g2 = tid >> 4, l2 = tid & 15;
                for (int r0 = 0; r0 < kM; r0 += 16) {
                    int r = r0 + g2;
                    const float* wr = W + (size_t)r * kW + 1024;
                    float ca = 0.f;
                    for (int k2 = l2 * 4; k2 < kM; k2 += 64) {
                        float4 w4 = *(const float4*)(wr + k2);
                        float4 x4 = *(const float4*)&Xb[k2];
                        ca = fmaf(w4.x, x4.x, ca); ca = fmaf(w4.y, x4.y, ca);
                        ca = fmaf(w4.z, x4.z, ca); ca = fmaf(w4.w, x4.w, ca);
                    }
                    ca += __shfl_xor(ca, 1); ca += __shfl_xor(ca, 2);
                    ca += __shfl_xor(ca, 4); ca += __shfl_xor(ca, 8);
                    if (l2 == 0) Cs[wk * kCsStride + r] = ca;
                }
                __syncthreads();
                if (tid == 0) {
                    slot_src[wk] = t;
                    empty_p[wk] = nz_sh ? 0.f : 1.f;
                }
            }
        }
        __syncthreads();
    }

    // epilogue: overwrite written slots only (bulk copy done in phase 1)
    for (int s = 0; s < kSlots; ++s) {
        int ts = slot_src[s];
        if (ts >= 0) {
            float* dst = out_hm + (size_t)(b * kSlots + s) * kM;
            dst[tid] = states[(size_t)(b * kN + ts) * kM + tid];
            dst[tid + 256] = states[(size_t)(b * kN + ts) * kM + tid + 256];
        }
    }
}

// ---------------------------------------------------------------------------
extern "C" void kernel_launch(void* const* d_in, const int* in_sizes, int n_in,
                              void* d_out, int out_size, void* d_ws, size_t ws_size,
                              hipStream_t stream)
{
    const float* his_mem      = (const float*)d_in[0];
    const float* states       = (const float*)d_in[1];
    const float* states_mask  = (const float*)d_in[2];
    const float* global_trace = (const float*)d_in[3];
    const float* null_mem     = (const float*)d_in[4];
    const float* gumbel_u     = (const float*)d_in[5];
    const float* attn_W       = (const float*)d_in[6];
    const float* attn_b       = (const float*)d_in[7];
    const float* v            = (const float*)d_in[8];

    // ws layout (~42 MB):
    //   C0      [256*16*512] f32  ( 8 MB)
    //   qCache  [8192*512]   f32  (16 MB)
    //   cwCache [8192*512]   f32  (16 MB)
    //   cnt_g[256] | ambT_g[256*128] | stepNz[8192] | bar[64*16]
    float* C0 = (float*)d_ws;
    float* qCache = C0 + (size_t)kB * kS * kM;
    float* cwCache = qCache + (size_t)kCap * kM;
    int* cnt_g = (int*)(cwCache + (size_t)kCap * kM);
    int* ambT_g = cnt_g + kB;
    int* stepNz = ambT_g + kB * kMaxA;
    unsigned* bar = (unsigned*)(stepNz + kCap);

    hipMemsetAsync(bar, 0, 64 * kBarStride * sizeof(unsigned), stream);
    fused_k<<<kGrid, 256, 0, stream>>>(his_mem, states, states_mask,
                                       global_trace, null_mem, gumbel_u, attn_W,
                                       attn_b, v, (float*)d_out, C0, qCache,
                                       cwCache, cnt_g, ambT_g, stepNz, bar);
}